// Round 14
// baseline (169.328 us; speedup 1.0000x reference)
//
#include <hip/hip_runtime.h>
#include <hip/hip_bf16.h>
#include <math.h>

#define LSEQ 2048
#define DMODEL 256
#define NH 8
#define HD 32

typedef __attribute__((ext_vector_type(8))) short bf16x8;
typedef __attribute__((ext_vector_type(4))) float f32x4;

#define MFMA __builtin_amdgcn_mfma_f32_16x16x32_bf16

__device__ __forceinline__ short f2bf(float x) {
  __hip_bfloat16 h = __float2bfloat16(x);
  return __builtin_bit_cast(short, h);
}
__device__ __forceinline__ float bf2f(short s) {
  __hip_bfloat16 h = __builtin_bit_cast(__hip_bfloat16, s);
  return __bfloat162float(h);
}
__device__ __forceinline__ short bftrunc(float x) {      // truncating f32->bf16
  return (short)(__builtin_bit_cast(unsigned int, x) >> 16);
}
// bare v_exp_f32 (2^x) — skip OCML denormal fixup (underflowed p contribute 0)
__device__ __forceinline__ float fexp2(float x) {
#if __has_builtin(__builtin_amdgcn_exp2f)
  return __builtin_amdgcn_exp2f(x);
#else
  return __expf(x * 0.6931471805599453f);
#endif
}
__device__ __forceinline__ float flog2(float x) {
#if __has_builtin(__builtin_amdgcn_logf)
  return __builtin_amdgcn_logf(x);
#else
  return __logf(x) * 1.4426950408889634f;
#endif
}

// ---- aux: Wqkv -> bf16, Wo -> split bf16, prior tables, disc zero ----
__global__ __launch_bounds__(256) void aux_kernel(
    const float* __restrict__ Wq, const float* __restrict__ Wk,
    const float* __restrict__ Wv, const float* __restrict__ Wo,
    const float* __restrict__ u,
    short* __restrict__ Wh,
    short* __restrict__ Woh, short* __restrict__ Wol,
    float* __restrict__ Eb, float* __restrict__ Zb,
    float* __restrict__ disc)
{
  __shared__ float Cs[LSEQ];
  __shared__ float part[256];
  const int tid = threadIdx.x;
  if (blockIdx.x < 256) {
    const int i4 = (blockIdx.x * 256 + tid) * 4;
    if (i4 < 196608) {
      int row = i4 >> 8, col = i4 & 255;
      const float* W = (row < 256) ? Wq : (row < 512) ? Wk : Wv;
      float4 v = *(const float4*)(W + (row & 255) * 256 + col);
      *(short4*)(Wh + i4) = make_short4(f2bf(v.x), f2bf(v.y), f2bf(v.z), f2bf(v.w));
    } else {
      int j = i4 - 196608;
      float4 v = *(const float4*)(Wo + j);
      short h0 = f2bf(v.x), h1 = f2bf(v.y), h2 = f2bf(v.z), h3 = f2bf(v.w);
      *(short4*)(Woh + j) = make_short4(h0, h1, h2, h3);
      *(short4*)(Wol + j) = make_short4(bftrunc(v.x - bf2f(h0)), bftrunc(v.y - bf2f(h1)),
                                        bftrunc(v.z - bf2f(h2)), bftrunc(v.w - bf2f(h3)));
    }
    return;
  }
  const int h = blockIdx.x - 256;
  const float uu = u[h];
  const float den = 2.0f * (uu * uu + 1e-6f);
  float e[8]; float run = 0.f;
  const int base = tid * 8;
#pragma unroll
  for (int j = 0; j < 8; ++j) {
    float d = (float)(base + j);
    e[j] = __expf(-(d * d) / den);
    run += e[j];
  }
  part[tid] = run;
  __syncthreads();
  for (int off = 1; off < 256; off <<= 1) {
    float v = (tid >= off) ? part[tid - off] : 0.f;
    __syncthreads();
    part[tid] += v;
    __syncthreads();
  }
  float c = part[tid] - run;
#pragma unroll
  for (int j = 0; j < 8; ++j) {
    c += e[j];
    Cs[base + j] = c;
    Eb[h * LSEQ + base + j] = e[j];
  }
  __syncthreads();
  const float E0 = Cs[0];
  for (int i = tid; i < LSEQ; i += 256) {
    float s = Cs[i] + Cs[LSEQ - 1 - i] - E0;
    Zb[h * LSEQ + i] = 1.0f / (s + 1e-6f);
  }
  for (int i = tid; i < 512; i += 256) disc[h * 512 + i] = 0.f;
}

// ---------------- fused QKV GEMM (pure bf16 MFMA, LDS-free) ------------------
__global__ __launch_bounds__(256) void qkv_gemm(
    const float* __restrict__ x,
    const short* __restrict__ Bh,
    const float* __restrict__ bq, const float* __restrict__ bk,
    const float* __restrict__ bv,
    short* __restrict__ Qf, short* __restrict__ Kf, short* __restrict__ Vf)
{
  const int tid = threadIdx.x, w = tid >> 6, lane = tid & 63;
  const int l15 = lane & 15, q4 = lane >> 4;
  const int m0 = blockIdx.x * 64, n0 = blockIdx.y * 64;
  const int mrow = m0 + w * 16 + l15;
  f32x4 acc[4] = {{0,0,0,0},{0,0,0,0},{0,0,0,0},{0,0,0,0}};
  for (int k0 = 0; k0 < 256; k0 += 32) {
    const float* xp = &x[(size_t)mrow * 256 + k0 + q4 * 8];
    float4 a = *(const float4*)xp;
    float4 c = *(const float4*)(xp + 4);
    bf16x8 ah;
    ah[0] = f2bf(a.x); ah[1] = f2bf(a.y); ah[2] = f2bf(a.z); ah[3] = f2bf(a.w);
    ah[4] = f2bf(c.x); ah[5] = f2bf(c.y); ah[6] = f2bf(c.z); ah[7] = f2bf(c.w);
#pragma unroll
    for (int nt = 0; nt < 4; ++nt) {
      const size_t bi = (size_t)(n0 + nt * 16 + l15) * 256 + k0 + q4 * 8;
      bf16x8 bh = *(const bf16x8*)&Bh[bi];
      acc[nt] = MFMA(ah, bh, acc[nt], 0, 0, 0);
    }
  }
  const int type = n0 >> 8;        // 0=Q 1=K 2=V
  const int n0l = n0 & 255;
  const float* bias = (type == 0) ? bq : (type == 1) ? bk : bv;
  const float qls = 0.25503489f;   // (1/sqrt(32)) * log2(e)
#pragma unroll
  for (int nt = 0; nt < 4; ++nt) {
    const int col = n0l + nt * 16 + l15;
    const float bvv = bias[col];
    const int hh = col >> 5, dloc = col & 31;
#pragma unroll
    for (int r = 0; r < 4; ++r) {
      const int m = m0 + w * 16 + q4 * 4 + r;
      float v = acc[nt][r] + bvv;
      const int bb = m >> 11, mm = m & 2047, rr = mm & 15;
      if (type == 2) {
        const int kt128 = mm >> 7, low7 = mm & 127;
        const int wv = (low7 >> 4) & 3, ph = low7 >> 6;
        const int c = ph * 16 + rr;
        const size_t idx =
          ((((((size_t)bb * 8 + hh) * 16 + kt128) * 4 + wv) * 2 + (dloc >> 4)) * 64
           + (c >> 3) * 16 + (dloc & 15)) * 8 + (c & 7);
        Vf[idx] = f2bf(v);
      } else if (type == 0) {
        const int qblk = mm >> 5, rg = (mm >> 4) & 1;
        const size_t idx =
          (((((size_t)bb * 8 + hh) * 64 + qblk) * 2 + rg) * 64
           + (dloc >> 3) * 16 + rr) * 8 + (dloc & 7);
        Qf[idx] = f2bf(v * qls);
      } else {
        const int g = mm >> 4;
        const size_t idx =
          ((((size_t)bb * 8 + hh) * 128 + g) * 64
           + (dloc >> 3) * 16 + rr) * 8 + (dloc & 7);
        Kf[idx] = f2bf(v);
      }
    }
  }
}

// ---------------- output GEMM (split-bf16 MFMA, fp32 out) --------------------
__global__ __launch_bounds__(256) void out_gemm(
    const short* __restrict__ Ah, const short* __restrict__ Al,
    const short* __restrict__ Bh, const short* __restrict__ Bl,
    const float* __restrict__ bias, float* __restrict__ C)
{
  const int tid = threadIdx.x, w = tid >> 6, lane = tid & 63;
  const int l15 = lane & 15, q4 = lane >> 4;
  const int m0 = blockIdx.x * 64, n0 = blockIdx.y * 64;
  const int mrow = m0 + w * 16 + l15;
  f32x4 acc[4] = {{0,0,0,0},{0,0,0,0},{0,0,0,0},{0,0,0,0}};
  for (int k0 = 0; k0 < 256; k0 += 32) {
    bf16x8 ah = *(const bf16x8*)&Ah[(size_t)mrow * 256 + k0 + q4 * 8];
    bf16x8 al = *(const bf16x8*)&Al[(size_t)mrow * 256 + k0 + q4 * 8];
#pragma unroll
    for (int nt = 0; nt < 4; ++nt) {
      const size_t bi = (size_t)(n0 + nt * 16 + l15) * 256 + k0 + q4 * 8;
      bf16x8 bh = *(const bf16x8*)&Bh[bi];
      bf16x8 bl = *(const bf16x8*)&Bl[bi];
      acc[nt] = MFMA(ah, bh, acc[nt], 0, 0, 0);
      acc[nt] = MFMA(al, bh, acc[nt], 0, 0, 0);
      acc[nt] = MFMA(ah, bl, acc[nt], 0, 0, 0);
    }
  }
#pragma unroll
  for (int nt = 0; nt < 4; ++nt) {
    const int col = n0 + nt * 16 + l15;
    const float bvv = bias[col];
#pragma unroll
    for (int r = 0; r < 4; ++r) {
      const int m = m0 + w * 16 + q4 * 4 + r;
      C[(size_t)m * 256 + col] = acc[nt][r] + bvv;
    }
  }
}

// ---------------- barrier-free MFMA flash attention + discrepancy ------------
// Round-13 structure + ONE-ITERATION REGISTER PREFETCH (rotate) in both passes:
// iteration i loads iteration i+1's K/V fragments (index wrapped, branchless),
// so first use trails issue by a full body (~400 cyc) and vmcnt is satisfied
// on arrival. Attacks the serial load->use chain since TLP is pinned (~10
// waves/CU regardless of launch_bounds/grid — r9/r13 evidence).
__global__ __launch_bounds__(256, 4) void attn_kernel(
    const short* __restrict__ Qf, const short* __restrict__ Kf,
    const short* __restrict__ Vf,
    const float* __restrict__ Eb, const float* __restrict__ Zb,
    short* __restrict__ Ohb, short* __restrict__ Olb,
    float* __restrict__ disc)
{
  __shared__ short Pt[4][32][40];   // per-wave P tile (reused as Ored)
  __shared__ float Elds[192];
  __shared__ float dcol[LSEQ];
  __shared__ float lpart[4][32];
  __shared__ float izlds[32];

  const int tid = threadIdx.x, w = tid >> 6, lane = tid & 63;
  const int l15 = lane & 15, q4 = lane >> 4;
  // ---- XCD swizzle: flat = x + 64*(y + 8*z); xcd = flat&7 = group&7 ----
  const int flat = blockIdx.x + 64 * (blockIdx.y + 8 * blockIdx.z);
  const int slot = flat >> 3;
  const int g = (flat & 7) | ((slot >> 6) << 3);   // 0..15
  const int h = g & 7, b = g >> 3;
  const int q0 = (slot & 63) * 32;
  const int bh = b * NH + h;

  for (int i = tid; i < LSEQ; i += 256) dcol[i] = 0.f;
  if (tid < 192) Elds[tid] = Eb[h * LSEQ + tid];
  if (tid < 32)  izlds[tid] = Zb[h * LSEQ + q0 + tid];

  const bf16x8* Qf8 = (const bf16x8*)Qf;
  const bf16x8* Kf8 = (const bf16x8*)Kf;
  const bf16x8* Vf8 = (const bf16x8*)Vf;

  bf16x8 qh[2];
#pragma unroll
  for (int rg = 0; rg < 2; ++rg)
    qh[rg] = Qf8[((((size_t)bh * 64 + (q0 >> 5)) * 2 + rg)) * 64 + lane];
  __syncthreads();

  const size_t kfb = (size_t)bh * 128;   // K group base
  const size_t vfb = (size_t)bh * 16;    // V kt128 base

  // ---- pass 1: per-wave k-partial row sums of 2^s (prefetch rotate) ----
  float lac[2][4] = {{0,0,0,0},{0,0,0,0}};
  bf16x8 k0 = Kf8[(kfb + 0 + w) * 64 + lane];
  bf16x8 k1 = Kf8[(kfb + 4 + w) * 64 + lane];
  for (int kt = 0; kt < LSEQ; kt += 128) {
    const int nk = ((kt + 128) & (LSEQ - 1)) >> 4;   // wraps to 0 on last iter
    bf16x8 nk0 = Kf8[(kfb + nk + w) * 64 + lane];
    bf16x8 nk1 = Kf8[(kfb + nk + 4 + w) * 64 + lane];
#pragma unroll
    for (int rg = 0; rg < 2; ++rg) {
      f32x4 s0 = {0.f, 0.f, 0.f, 0.f};
      s0 = MFMA(qh[rg], k0, s0, 0, 0, 0);
      f32x4 s1 = {0.f, 0.f, 0.f, 0.f};
      s1 = MFMA(qh[rg], k1, s1, 0, 0, 0);
#pragma unroll
      for (int r = 0; r < 4; ++r) lac[rg][r] += fexp2(s0[r]) + fexp2(s1[r]);
    }
    k0 = nk0;
    k1 = nk1;
  }
#pragma unroll
  for (int rg = 0; rg < 2; ++rg)
#pragma unroll
    for (int r = 0; r < 4; ++r) {
      float v = lac[rg][r];
      v += __shfl_xor(v, 1); v += __shfl_xor(v, 2);
      v += __shfl_xor(v, 4); v += __shfl_xor(v, 8);
      lac[rg][r] = v;
    }
  if (l15 == 0) {
#pragma unroll
    for (int rg = 0; rg < 2; ++rg)
#pragma unroll
      for (int r = 0; r < 4; ++r) lpart[w][rg * 16 + q4 * 4 + r] = lac[rg][r];
  }
  __syncthreads();
  f32x4 sinit[2];
#pragma unroll
  for (int rg = 0; rg < 2; ++rg)
#pragma unroll
    for (int r = 0; r < 4; ++r) {
      const int qi = rg * 16 + q4 * 4 + r;
      sinit[rg][r] = -flog2(lpart[0][qi] + lpart[1][qi] + lpart[2][qi] + lpart[3][qi]);
    }

  // ---- pass 2: p = 2^(s + mlog2), disc col sums, O += P*V (prefetch rotate) ----
  f32x4 oacc[2][2] = {{{0,0,0,0},{0,0,0,0}},{{0,0,0,0},{0,0,0,0}}};
  bf16x8 kh0 = Kf8[(kfb + 0 + w) * 64 + lane];
  bf16x8 kh1 = Kf8[(kfb + 4 + w) * 64 + lane];
  bf16x8 vb0 = Vf8[((vfb * 4 + w) * 2 + 0) * 64 + lane];
  bf16x8 vb1 = Vf8[((vfb * 4 + w) * 2 + 1) * 64 + lane];
  for (int kt = 0; kt < LSEQ; kt += 128) {
    const int nt128 = ((kt + 128) & (LSEQ - 1));     // wraps to 0 on last iter
    bf16x8 nkh0 = Kf8[(kfb + (nt128 >> 4) + w) * 64 + lane];
    bf16x8 nkh1 = Kf8[(kfb + (nt128 >> 4) + 4 + w) * 64 + lane];
    bf16x8 nvb0 = Vf8[(((vfb + (nt128 >> 7)) * 4 + w) * 2 + 0) * 64 + lane];
    bf16x8 nvb1 = Vf8[(((vfb + (nt128 >> 7)) * 4 + w) * 2 + 1) * 64 + lane];
#pragma unroll
    for (int ph = 0; ph < 2; ++ph) {
      bf16x8 kbh = ph ? kh1 : kh0;
      const int c0 = kt + ph * 64 + w * 16;
      const int kg = c0 + l15;
      const int dd = c0 - q0;
      const bool near = (dd >= -96) && (dd <= 96);
      float dsum = 0.f;
#pragma unroll
      for (int rg = 0; rg < 2; ++rg) {
        f32x4 s = sinit[rg];
        s = MFMA(qh[rg], kbh, s, 0, 0, 0);
#pragma unroll
        for (int r = 0; r < 4; ++r) {
          float p = fexp2(s[r]);
          Pt[w][rg * 16 + q4 * 4 + r][ph * 16 + l15] = bftrunc(p);
          if (near) {
            int qrow = q0 + rg * 16 + q4 * 4 + r;
            int dist = (qrow >= kg) ? (qrow - kg) : (kg - qrow);
            dsum += fabsf(p - Elds[dist] * izlds[rg * 16 + q4 * 4 + r]);
          } else {
            dsum += p;
          }
        }
      }
      dsum += __shfl_xor(dsum, 16);
      dsum += __shfl_xor(dsum, 32);
      if (q4 == 0) atomicAdd(&dcol[kg], dsum);
    }
#pragma unroll
    for (int rg = 0; rg < 2; ++rg) {
      bf16x8 pa = *(const bf16x8*)&Pt[w][rg * 16 + l15][q4 * 8];
      oacc[rg][0] = MFMA(pa, vb0, oacc[rg][0], 0, 0, 0);
      oacc[rg][1] = MFMA(pa, vb1, oacc[rg][1], 0, 0, 0);
    }
    kh0 = nkh0; kh1 = nkh1; vb0 = nvb0; vb1 = nvb1;
  }

  // ---- epilogue: cross-wave O reduce (k-partials), split-bf16 O store ----
  __syncthreads();
  float* Ored = (float*)&Pt[0][0][0];   // [4][32][17] floats = 8704B, fits
#pragma unroll
  for (int dt = 0; dt < 2; ++dt) {
#pragma unroll
    for (int rg = 0; rg < 2; ++rg)
#pragma unroll
      for (int r = 0; r < 4; ++r)
        Ored[(w * 32 + rg * 16 + q4 * 4 + r) * 17 + l15] = oacc[rg][dt][r];
    __syncthreads();
    for (int t = tid; t < 512; t += 256) {
      const int q = t >> 4, d = t & 15;
      float v = Ored[(q) * 17 + d] + Ored[(32 + q) * 17 + d] +
                Ored[(64 + q) * 17 + d] + Ored[(96 + q) * 17 + d];
      const size_t oo = ((size_t)b * LSEQ + q0 + q) * DMODEL + h * HD + dt * 16 + d;
      short hi = f2bf(v);
      Ohb[oo] = hi;
      Olb[oo] = bftrunc(v - bf2f(hi));
    }
    __syncthreads();
  }
  const float sc = 1.0f / (float)(NH * LSEQ);
  for (int i = tid; i < LSEQ; i += 256)
    atomicAdd(&disc[(size_t)b * LSEQ + i], dcol[i] * sc);
}

extern "C" void kernel_launch(void* const* d_in, const int* in_sizes, int n_in,
                              void* d_out, int out_size, void* d_ws, size_t ws_size,
                              hipStream_t stream)
{
  const float* x  = (const float*)d_in[0];
  const float* Wq = (const float*)d_in[1];
  const float* bq = (const float*)d_in[2];
  const float* Wk = (const float*)d_in[3];
  const float* bk = (const float*)d_in[4];
  const float* Wv = (const float*)d_in[5];
  const float* bv = (const float*)d_in[6];
  const float* u  = (const float*)d_in[7];
  const float* Wo = (const float*)d_in[8];
  const float* bo = (const float*)d_in[9];

  float* out  = (float*)d_out;
  float* disc = out + (size_t)2 * LSEQ * DMODEL;

  char* w8 = (char*)d_ws;
  const size_t MB = 1u << 20;
  short* Qfb = (short*)(w8);               // 2MB each
  short* Kfb = (short*)(w8 + 2 * MB);
  short* Vfb = (short*)(w8 + 4 * MB);
  short* Ohb = (short*)(w8 + 6 * MB);
  short* Olb = (short*)(w8 + 8 * MB);
  short* Wh  = (short*)(w8 + 10 * MB);                 // 384KB (Wqkv bf16)
  short* Woh = (short*)(w8 + 10 * MB + 393216);        // 128KB
  short* Wol = (short*)(w8 + 10 * MB + 524288);        // 128KB
  float* Eb  = (float*)(w8 + 11 * MB);                 // 64KB
  float* Zb  = (float*)(w8 + 11 * MB + 65536);         // 64KB

  aux_kernel<<<264, 256, 0, stream>>>(Wq, Wk, Wv, Wo, u, Wh, Woh, Wol,
                                      Eb, Zb, disc);
  qkv_gemm<<<dim3(64, 12), 256, 0, stream>>>(x, Wh, bq, bk, bv,
                                             Qfb, Kfb, Vfb);
  attn_kernel<<<dim3(LSEQ / 32, NH, 2), 256, 0, stream>>>(Qfb, Kfb, Vfb,
                                                          Eb, Zb, Ohb, Olb, disc);
  out_gemm<<<dim3(64, 4), 256, 0, stream>>>(Ohb, Olb, Woh, Wol, bo, out);
}

// Round 15
// 157.844 us; speedup vs baseline: 1.0728x; 1.0728x over previous
//
#include <hip/hip_runtime.h>
#include <hip/hip_bf16.h>
#include <math.h>

#define LSEQ 2048
#define DMODEL 256
#define NH 8
#define HD 32

typedef __attribute__((ext_vector_type(8))) short bf16x8;
typedef __attribute__((ext_vector_type(4))) float f32x4;

#define MFMA __builtin_amdgcn_mfma_f32_16x16x32_bf16

__device__ __forceinline__ short f2bf(float x) {
  __hip_bfloat16 h = __float2bfloat16(x);
  return __builtin_bit_cast(short, h);
}
__device__ __forceinline__ float bf2f(short s) {
  __hip_bfloat16 h = __builtin_bit_cast(__hip_bfloat16, s);
  return __bfloat162float(h);
}
__device__ __forceinline__ short bftrunc(float x) {      // truncating f32->bf16
  return (short)(__builtin_bit_cast(unsigned int, x) >> 16);
}
// bare v_exp_f32 (2^x) — skip OCML denormal fixup (underflowed p contribute 0)
__device__ __forceinline__ float fexp2(float x) {
#if __has_builtin(__builtin_amdgcn_exp2f)
  return __builtin_amdgcn_exp2f(x);
#else
  return __expf(x * 0.6931471805599453f);
#endif
}
__device__ __forceinline__ float flog2(float x) {
#if __has_builtin(__builtin_amdgcn_logf)
  return __builtin_amdgcn_logf(x);
#else
  return __logf(x) * 1.4426950408889634f;
#endif
}

// ---- aux: Wqkv -> bf16, Wo -> split bf16, prior tables, disc zero ----
__global__ __launch_bounds__(256) void aux_kernel(
    const float* __restrict__ Wq, const float* __restrict__ Wk,
    const float* __restrict__ Wv, const float* __restrict__ Wo,
    const float* __restrict__ u,
    short* __restrict__ Wh,
    short* __restrict__ Woh, short* __restrict__ Wol,
    float* __restrict__ Eb, float* __restrict__ Zb,
    float* __restrict__ disc)
{
  __shared__ float Cs[LSEQ];
  __shared__ float part[256];
  const int tid = threadIdx.x;
  if (blockIdx.x < 256) {
    const int i4 = (blockIdx.x * 256 + tid) * 4;
    if (i4 < 196608) {
      int row = i4 >> 8, col = i4 & 255;
      const float* W = (row < 256) ? Wq : (row < 512) ? Wk : Wv;
      float4 v = *(const float4*)(W + (row & 255) * 256 + col);
      *(short4*)(Wh + i4) = make_short4(f2bf(v.x), f2bf(v.y), f2bf(v.z), f2bf(v.w));
    } else {
      int j = i4 - 196608;
      float4 v = *(const float4*)(Wo + j);
      short h0 = f2bf(v.x), h1 = f2bf(v.y), h2 = f2bf(v.z), h3 = f2bf(v.w);
      *(short4*)(Woh + j) = make_short4(h0, h1, h2, h3);
      *(short4*)(Wol + j) = make_short4(bftrunc(v.x - bf2f(h0)), bftrunc(v.y - bf2f(h1)),
                                        bftrunc(v.z - bf2f(h2)), bftrunc(v.w - bf2f(h3)));
    }
    return;
  }
  const int h = blockIdx.x - 256;
  const float uu = u[h];
  const float den = 2.0f * (uu * uu + 1e-6f);
  float e[8]; float run = 0.f;
  const int base = tid * 8;
#pragma unroll
  for (int j = 0; j < 8; ++j) {
    float d = (float)(base + j);
    e[j] = __expf(-(d * d) / den);
    run += e[j];
  }
  part[tid] = run;
  __syncthreads();
  for (int off = 1; off < 256; off <<= 1) {
    float v = (tid >= off) ? part[tid - off] : 0.f;
    __syncthreads();
    part[tid] += v;
    __syncthreads();
  }
  float c = part[tid] - run;
#pragma unroll
  for (int j = 0; j < 8; ++j) {
    c += e[j];
    Cs[base + j] = c;
    Eb[h * LSEQ + base + j] = e[j];
  }
  __syncthreads();
  const float E0 = Cs[0];
  for (int i = tid; i < LSEQ; i += 256) {
    float s = Cs[i] + Cs[LSEQ - 1 - i] - E0;
    Zb[h * LSEQ + i] = 1.0f / (s + 1e-6f);
  }
  for (int i = tid; i < 512; i += 256) disc[h * 512 + i] = 0.f;
}

// ---------------- fused QKV GEMM (pure bf16 MFMA, LDS-free) ------------------
// Downstream attention consumes bf16 Q/K/V anyway, so the GEMM runs pure bf16
// (1 MFMA per tile, no split). Epilogue stores fragment-major (the exact
// 64-lane order the attn waves consume).
__global__ __launch_bounds__(256) void qkv_gemm(
    const float* __restrict__ x,
    const short* __restrict__ Bh,
    const float* __restrict__ bq, const float* __restrict__ bk,
    const float* __restrict__ bv,
    short* __restrict__ Qf, short* __restrict__ Kf, short* __restrict__ Vf)
{
  const int tid = threadIdx.x, w = tid >> 6, lane = tid & 63;
  const int l15 = lane & 15, q4 = lane >> 4;
  const int m0 = blockIdx.x * 64, n0 = blockIdx.y * 64;
  const int mrow = m0 + w * 16 + l15;
  f32x4 acc[4] = {{0,0,0,0},{0,0,0,0},{0,0,0,0},{0,0,0,0}};
  for (int k0 = 0; k0 < 256; k0 += 32) {
    const float* xp = &x[(size_t)mrow * 256 + k0 + q4 * 8];
    float4 a = *(const float4*)xp;
    float4 c = *(const float4*)(xp + 4);
    bf16x8 ah;
    ah[0] = f2bf(a.x); ah[1] = f2bf(a.y); ah[2] = f2bf(a.z); ah[3] = f2bf(a.w);
    ah[4] = f2bf(c.x); ah[5] = f2bf(c.y); ah[6] = f2bf(c.z); ah[7] = f2bf(c.w);
#pragma unroll
    for (int nt = 0; nt < 4; ++nt) {
      const size_t bi = (size_t)(n0 + nt * 16 + l15) * 256 + k0 + q4 * 8;
      bf16x8 bh = *(const bf16x8*)&Bh[bi];
      acc[nt] = MFMA(ah, bh, acc[nt], 0, 0, 0);
    }
  }
  const int type = n0 >> 8;        // 0=Q 1=K 2=V
  const int n0l = n0 & 255;
  const float* bias = (type == 0) ? bq : (type == 1) ? bk : bv;
  const float qls = 0.25503489f;   // (1/sqrt(32)) * log2(e)
#pragma unroll
  for (int nt = 0; nt < 4; ++nt) {
    const int col = n0l + nt * 16 + l15;
    const float bvv = bias[col];
    const int hh = col >> 5, dloc = col & 31;
#pragma unroll
    for (int r = 0; r < 4; ++r) {
      const int m = m0 + w * 16 + q4 * 4 + r;
      float v = acc[nt][r] + bvv;
      const int bb = m >> 11, mm = m & 2047, rr = mm & 15;
      if (type == 2) {
        const int kt128 = mm >> 7, low7 = mm & 127;
        const int wv = (low7 >> 4) & 3, ph = low7 >> 6;
        const int c = ph * 16 + rr;
        const size_t idx =
          ((((((size_t)bb * 8 + hh) * 16 + kt128) * 4 + wv) * 2 + (dloc >> 4)) * 64
           + (c >> 3) * 16 + (dloc & 15)) * 8 + (c & 7);
        Vf[idx] = f2bf(v);
      } else if (type == 0) {
        const int qblk = mm >> 5, rg = (mm >> 4) & 1;
        const size_t idx =
          (((((size_t)bb * 8 + hh) * 64 + qblk) * 2 + rg) * 64
           + (dloc >> 3) * 16 + rr) * 8 + (dloc & 7);
        Qf[idx] = f2bf(v * qls);
      } else {
        const int g = mm >> 4;
        const size_t idx =
          ((((size_t)bb * 8 + hh) * 128 + g) * 64
           + (dloc >> 3) * 16 + rr) * 8 + (dloc & 7);
        Kf[idx] = f2bf(v);
      }
    }
  }
}

// ---------------- output GEMM (split-bf16 MFMA, fp32 out) --------------------
__global__ __launch_bounds__(256) void out_gemm(
    const short* __restrict__ Ah, const short* __restrict__ Al,
    const short* __restrict__ Bh, const short* __restrict__ Bl,
    const float* __restrict__ bias, float* __restrict__ C)
{
  const int tid = threadIdx.x, w = tid >> 6, lane = tid & 63;
  const int l15 = lane & 15, q4 = lane >> 4;
  const int m0 = blockIdx.x * 64, n0 = blockIdx.y * 64;
  const int mrow = m0 + w * 16 + l15;
  f32x4 acc[4] = {{0,0,0,0},{0,0,0,0},{0,0,0,0},{0,0,0,0}};
  for (int k0 = 0; k0 < 256; k0 += 32) {
    bf16x8 ah = *(const bf16x8*)&Ah[(size_t)mrow * 256 + k0 + q4 * 8];
    bf16x8 al = *(const bf16x8*)&Al[(size_t)mrow * 256 + k0 + q4 * 8];
#pragma unroll
    for (int nt = 0; nt < 4; ++nt) {
      const size_t bi = (size_t)(n0 + nt * 16 + l15) * 256 + k0 + q4 * 8;
      bf16x8 bh = *(const bf16x8*)&Bh[bi];
      bf16x8 bl = *(const bf16x8*)&Bl[bi];
      acc[nt] = MFMA(ah, bh, acc[nt], 0, 0, 0);
      acc[nt] = MFMA(al, bh, acc[nt], 0, 0, 0);
      acc[nt] = MFMA(ah, bl, acc[nt], 0, 0, 0);
    }
  }
#pragma unroll
  for (int nt = 0; nt < 4; ++nt) {
    const int col = n0 + nt * 16 + l15;
    const float bvv = bias[col];
#pragma unroll
    for (int r = 0; r < 4; ++r) {
      const int m = m0 + w * 16 + q4 * 4 + r;
      C[(size_t)m * 256 + col] = acc[nt][r] + bvv;
    }
  }
}

// ---------------- barrier-free MFMA flash attention + discrepancy ------------
// XCD swizzle + fragment-major loads. __launch_bounds__(256,4) keeps the
// allocator under 128 combined VGPR+AGPR. Register diet: single-buffer Pt,
// iz in LDS, no prefetch (r14 showed prefetch registers spill to scratch at
// this budget: WRITE_SIZE 12KB -> 73MB).
__global__ __launch_bounds__(256, 4) void attn_kernel(
    const short* __restrict__ Qf, const short* __restrict__ Kf,
    const short* __restrict__ Vf,
    const float* __restrict__ Eb, const float* __restrict__ Zb,
    short* __restrict__ Ohb, short* __restrict__ Olb,
    float* __restrict__ disc)
{
  __shared__ short Pt[4][32][40];   // per-wave P tile (reused as Ored)
  __shared__ float Elds[192];
  __shared__ float dcol[LSEQ];
  __shared__ float lpart[4][32];
  __shared__ float izlds[32];

  const int tid = threadIdx.x, w = tid >> 6, lane = tid & 63;
  const int l15 = lane & 15, q4 = lane >> 4;
  // ---- XCD swizzle: flat = x + 64*(y + 8*z); xcd = flat&7 = group&7 ----
  const int flat = blockIdx.x + 64 * (blockIdx.y + 8 * blockIdx.z);
  const int slot = flat >> 3;
  const int g = (flat & 7) | ((slot >> 6) << 3);   // 0..15
  const int h = g & 7, b = g >> 3;
  const int q0 = (slot & 63) * 32;
  const int bh = b * NH + h;

  for (int i = tid; i < LSEQ; i += 256) dcol[i] = 0.f;
  if (tid < 192) Elds[tid] = Eb[h * LSEQ + tid];
  if (tid < 32)  izlds[tid] = Zb[h * LSEQ + q0 + tid];

  const bf16x8* Qf8 = (const bf16x8*)Qf;
  const bf16x8* Kf8 = (const bf16x8*)Kf;
  const bf16x8* Vf8 = (const bf16x8*)Vf;

  bf16x8 qh[2];
#pragma unroll
  for (int rg = 0; rg < 2; ++rg)
    qh[rg] = Qf8[((((size_t)bh * 64 + (q0 >> 5)) * 2 + rg)) * 64 + lane];
  __syncthreads();

  const size_t kfb = (size_t)bh * 128;   // K group base
  const size_t vfb = (size_t)bh * 16;    // V kt128 base

  // ---- pass 1: per-wave k-partial row sums of 2^s ----
  float lac[2][4] = {{0,0,0,0},{0,0,0,0}};
#pragma unroll 2
  for (int kt = 0; kt < LSEQ; kt += 128) {
    bf16x8 k0 = Kf8[(kfb + (kt >> 4) + w) * 64 + lane];
    bf16x8 k1 = Kf8[(kfb + (kt >> 4) + 4 + w) * 64 + lane];
#pragma unroll
    for (int rg = 0; rg < 2; ++rg) {
      f32x4 s0 = {0.f, 0.f, 0.f, 0.f};
      s0 = MFMA(qh[rg], k0, s0, 0, 0, 0);
      f32x4 s1 = {0.f, 0.f, 0.f, 0.f};
      s1 = MFMA(qh[rg], k1, s1, 0, 0, 0);
#pragma unroll
      for (int r = 0; r < 4; ++r) lac[rg][r] += fexp2(s0[r]) + fexp2(s1[r]);
    }
  }
#pragma unroll
  for (int rg = 0; rg < 2; ++rg)
#pragma unroll
    for (int r = 0; r < 4; ++r) {
      float v = lac[rg][r];
      v += __shfl_xor(v, 1); v += __shfl_xor(v, 2);
      v += __shfl_xor(v, 4); v += __shfl_xor(v, 8);
      lac[rg][r] = v;
    }
  if (l15 == 0) {
#pragma unroll
    for (int rg = 0; rg < 2; ++rg)
#pragma unroll
      for (int r = 0; r < 4; ++r) lpart[w][rg * 16 + q4 * 4 + r] = lac[rg][r];
  }
  __syncthreads();
  f32x4 sinit[2];
#pragma unroll
  for (int rg = 0; rg < 2; ++rg)
#pragma unroll
    for (int r = 0; r < 4; ++r) {
      const int qi = rg * 16 + q4 * 4 + r;
      sinit[rg][r] = -flog2(lpart[0][qi] + lpart[1][qi] + lpart[2][qi] + lpart[3][qi]);
    }

  // ---- pass 2: p = 2^(s + mlog2), discrepancy col sums, O += P*V ----
  f32x4 oacc[2][2] = {{{0,0,0,0},{0,0,0,0}},{{0,0,0,0},{0,0,0,0}}};
#pragma unroll 2
  for (int kt = 0; kt < LSEQ; kt += 128) {
    bf16x8 kh0 = Kf8[(kfb + (kt >> 4) + w) * 64 + lane];
    bf16x8 kh1 = Kf8[(kfb + (kt >> 4) + 4 + w) * 64 + lane];
    bf16x8 vb0 = Vf8[(((vfb + (kt >> 7)) * 4 + w) * 2 + 0) * 64 + lane];
    bf16x8 vb1 = Vf8[(((vfb + (kt >> 7)) * 4 + w) * 2 + 1) * 64 + lane];
#pragma unroll
    for (int ph = 0; ph < 2; ++ph) {
      bf16x8 kbh = ph ? kh1 : kh0;
      const int c0 = kt + ph * 64 + w * 16;
      const int kg = c0 + l15;
      const int dd = c0 - q0;
      const bool near = (dd >= -96) && (dd <= 96);
      float dsum = 0.f;
#pragma unroll
      for (int rg = 0; rg < 2; ++rg) {
        f32x4 s = sinit[rg];
        s = MFMA(qh[rg], kbh, s, 0, 0, 0);
#pragma unroll
        for (int r = 0; r < 4; ++r) {
          float p = fexp2(s[r]);
          Pt[w][rg * 16 + q4 * 4 + r][ph * 16 + l15] = bftrunc(p);
          if (near) {
            int qrow = q0 + rg * 16 + q4 * 4 + r;
            int dist = (qrow >= kg) ? (qrow - kg) : (kg - qrow);
            dsum += fabsf(p - Elds[dist] * izlds[rg * 16 + q4 * 4 + r]);
          } else {
            dsum += p;
          }
        }
      }
      dsum += __shfl_xor(dsum, 16);
      dsum += __shfl_xor(dsum, 32);
      if (q4 == 0) atomicAdd(&dcol[kg], dsum);
    }
#pragma unroll
    for (int rg = 0; rg < 2; ++rg) {
      bf16x8 pa = *(const bf16x8*)&Pt[w][rg * 16 + l15][q4 * 8];
      oacc[rg][0] = MFMA(pa, vb0, oacc[rg][0], 0, 0, 0);
      oacc[rg][1] = MFMA(pa, vb1, oacc[rg][1], 0, 0, 0);
    }
  }

  // ---- epilogue: cross-wave O reduce (k-partials), split-bf16 O store ----
  __syncthreads();
  float* Ored = (float*)&Pt[0][0][0];   // [4][32][17] floats = 8704B, fits
#pragma unroll
  for (int dt = 0; dt < 2; ++dt) {
#pragma unroll
    for (int rg = 0; rg < 2; ++rg)
#pragma unroll
      for (int r = 0; r < 4; ++r)
        Ored[(w * 32 + rg * 16 + q4 * 4 + r) * 17 + l15] = oacc[rg][dt][r];
    __syncthreads();
    for (int t = tid; t < 512; t += 256) {
      const int q = t >> 4, d = t & 15;
      float v = Ored[(q) * 17 + d] + Ored[(32 + q) * 17 + d] +
                Ored[(64 + q) * 17 + d] + Ored[(96 + q) * 17 + d];
      const size_t oo = ((size_t)b * LSEQ + q0 + q) * DMODEL + h * HD + dt * 16 + d;
      short hi = f2bf(v);
      Ohb[oo] = hi;
      Olb[oo] = bftrunc(v - bf2f(hi));
    }
    __syncthreads();
  }
  const float sc = 1.0f / (float)(NH * LSEQ);
  for (int i = tid; i < LSEQ; i += 256)
    atomicAdd(&disc[(size_t)b * LSEQ + i], dcol[i] * sc);
}

extern "C" void kernel_launch(void* const* d_in, const int* in_sizes, int n_in,
                              void* d_out, int out_size, void* d_ws, size_t ws_size,
                              hipStream_t stream)
{
  const float* x  = (const float*)d_in[0];
  const float* Wq = (const float*)d_in[1];
  const float* bq = (const float*)d_in[2];
  const float* Wk = (const float*)d_in[3];
  const float* bk = (const float*)d_in[4];
  const float* Wv = (const float*)d_in[5];
  const float* bv = (const float*)d_in[6];
  const float* u  = (const float*)d_in[7];
  const float* Wo = (const float*)d_in[8];
  const float* bo = (const float*)d_in[9];

  float* out  = (float*)d_out;
  float* disc = out + (size_t)2 * LSEQ * DMODEL;

  char* w8 = (char*)d_ws;
  const size_t MB = 1u << 20;
  short* Qfb = (short*)(w8);               // 2MB each
  short* Kfb = (short*)(w8 + 2 * MB);
  short* Vfb = (short*)(w8 + 4 * MB);
  short* Ohb = (short*)(w8 + 6 * MB);
  short* Olb = (short*)(w8 + 8 * MB);
  short* Wh  = (short*)(w8 + 10 * MB);                 // 384KB (Wqkv bf16)
  short* Woh = (short*)(w8 + 10 * MB + 393216);        // 128KB
  short* Wol = (short*)(w8 + 10 * MB + 524288);        // 128KB
  float* Eb  = (float*)(w8 + 11 * MB);                 // 64KB
  float* Zb  = (float*)(w8 + 11 * MB + 65536);         // 64KB

  aux_kernel<<<264, 256, 0, stream>>>(Wq, Wk, Wv, Wo, u, Wh, Woh, Wol,
                                      Eb, Zb, disc);
  qkv_gemm<<<dim3(64, 12), 256, 0, stream>>>(x, Wh, bq, bk, bv,
                                             Qfb, Kfb, Vfb);
  attn_kernel<<<dim3(LSEQ / 32, NH, 2), 256, 0, stream>>>(Qfb, Kfb, Vfb,
                                                          Eb, Zb, Ohb, Olb, disc);
  out_gemm<<<dim3(64, 4), 256, 0, stream>>>(Ohb, Olb, Woh, Wol, bo, out);
}